// Round 10
// baseline (639.333 us; speedup 1.0000x reference)
//
#include <hip/hip_runtime.h>
#include <math.h>

// B=1, S=4096, H=8, DH=40, D=320, fp32 in/out.
// ONE persistent kernel, 1024 blocks x 256 thr. Capacity argument: LDS 28.5KB
// + launch_bounds(256,4) (VGPR<=128) -> 4 blocks/CU x 256 CUs = 1024 = grid,
// so ALL blocks are co-resident regardless of dispatch order; manual
// device-scope grid barriers are safe (this is what cooperative launch would
// have checked; hipLaunchCooperativeKernel itself fails graph capture - R7).
//  A: QKV proj (R9's 128x64/BK=64 MFMA GEMM, 480 units) -> Qp/Kp [h][s][48]
//     (Q pre-scaled; pad = -32 offset trick), Vt [h][40][4096]
//  B: MFMA flash attn (R9 core), ks=4 split, sigma-permuted K staging so QK
//     C/D regs ARE PV A-frags, p = raw v_exp_f32, l via ones-row at dh=40
//  C: combine 4 partials -> Xo [s][320] bf16 (grid-stride)
//  D: out proj (R6's 64x64/BK=32 MFMA GEMM, 320 Beatty units) + bias -> fp32

#define NS 4096
#define ND 320
#define SCALE2 0.2281101152f      // log2(e)/sqrt(40)
#define HS48 196608               // 4096*48 per head
#define VTH 163840                // 40*4096 per head
#define XN 1310720

typedef __attribute__((ext_vector_type(8))) short bf16x8;
typedef __attribute__((ext_vector_type(16))) float f32x16;

static __device__ __forceinline__ unsigned short f2bru(float f) {
  return (unsigned short)((__builtin_bit_cast(unsigned int, f) + 0x8000u) >> 16);
}
static __device__ __forceinline__ unsigned int pk2ru(float a, float b) {
  unsigned int ua = __builtin_bit_cast(unsigned int, a) + 0x8000u;
  unsigned int ub = __builtin_bit_cast(unsigned int, b) + 0x8000u;
  return __builtin_amdgcn_perm(ub, ua, 0x07060302u);
}
static __device__ __forceinline__ unsigned int pk2t(float a, float b) {
  return __builtin_amdgcn_perm(__builtin_bit_cast(unsigned int, b),
                               __builtin_bit_cast(unsigned int, a), 0x07060302u);
}
static __device__ __forceinline__ float fexp2(float x) {
  return __builtin_amdgcn_exp2f(x);
}
static __device__ __forceinline__ bf16x8 ld8(const unsigned short* p) {
  union { uint2 u[2]; bf16x8 v; } c;
  c.u[0] = *(const uint2*)p;
  c.u[1] = *(const uint2*)(p + 4);
  return c.v;
}
static __device__ __forceinline__ uint4 ld16u(const unsigned short* p) {
  uint2 a = *(const uint2*)p, b = *(const uint2*)(p + 4);
  return make_uint4(a.x, a.y, b.x, b.y);
}
static __device__ __forceinline__ void st16(unsigned short* p, uint4 v) {
  *(uint2*)p = make_uint2(v.x, v.y);
  *(uint2*)(p + 4) = make_uint2(v.z, v.w);
}
// sigma: phys key (0..31) -> MFMA m-row so QK C/D regs land in PV A order
static __device__ __forceinline__ int sig32(int q) {
  int s = q >> 4, h2 = (q >> 3) & 1, j = q & 7;
  return (s << 4) | ((h2 ^ ((j >> 2) ^ h2)) << 3) | (((j >> 2) ^ ((j >> 2) ^ h2)) << 2) | (j & 3);
}
// NOTE: expression above simplifies to (s<<4)|((j>>2)<<3)|(h2<<2)|(j&3) —
// written out to keep the validated R6/R9 mapping explicit:
static __device__ __forceinline__ int sig32v(int q) {
  int s = q >> 4, h2 = (q >> 3) & 1, j = q & 7;
  return (s << 4) | ((j >> 2) << 3) | (h2 << 2) | (j & 3);
}

// device-scope grid barrier; safe because grid == residency capacity
static __device__ __forceinline__ void gridbar(unsigned int* c, unsigned int target) {
  __syncthreads();
  if (threadIdx.x == 0) {
    __threadfence();
    __hip_atomic_fetch_add(c, 1u, __ATOMIC_ACQ_REL, __HIP_MEMORY_SCOPE_AGENT);
    while (__hip_atomic_load(c, __ATOMIC_ACQUIRE, __HIP_MEMORY_SCOPE_AGENT) < target)
      __builtin_amdgcn_s_sleep(2);
  }
  __syncthreads();
}

__global__ __launch_bounds__(256, 4) void mega_kernel(
    const float* __restrict__ x, const float* __restrict__ Wq,
    const float* __restrict__ Wk, const float* __restrict__ Wv,
    const float* __restrict__ Wo, const float* __restrict__ bo,
    float* __restrict__ out,
    unsigned short* __restrict__ Qp, unsigned short* __restrict__ Kp,
    unsigned short* __restrict__ Vt, unsigned short* __restrict__ Op,
    unsigned short* __restrict__ Xo, float* __restrict__ Lp,
    unsigned int* __restrict__ bar) {
  __shared__ __align__(16) unsigned char smem[29184];
  const int b = blockIdx.x;
  const int t = threadIdx.x;
  const int w = t >> 6, l = t & 63, l31 = l & 31, hi = l >> 5;

  // ================= Phase A: QKV projection (480 units) =================
  if (b < 480) {
    const int zi = b >> 5;                   // 0..14
    const int z = zi / 5;
    const int bnn = (zi - z * 5) * 64;
    const int bm = (b & 31) * 128;
    const float* W = (z == 0) ? Wq : (z == 1) ? Wk : Wv;
    unsigned short* As = (unsigned short*)smem;            // 128*76
    unsigned short* Bs = (unsigned short*)(smem + 19456);  // 64*76
    const int m0 = w * 32;
    f32x16 acc0 = {0,0,0,0,0,0,0,0,0,0,0,0,0,0,0,0};
    f32x16 acc1 = {0,0,0,0,0,0,0,0,0,0,0,0,0,0,0,0};
    const unsigned short* af = As + (m0 + l31) * 76 + hi * 8;
    const unsigned short* bf0 = Bs + l31 * 76 + hi * 8;
    const unsigned short* bf1 = Bs + (32 + l31) * 76 + hi * 8;
    for (int k0 = 0; k0 < ND; k0 += 64) {
      __syncthreads();
#pragma unroll
      for (int i = 0; i < 4; i++) {          // A: 128 rows x 8 chunks(8)
        int c = t + i * 256;
        int row = c >> 3, kc = (c & 7) << 3;
        const float* g = x + (bm + row) * ND + k0 + kc;
        float4 v0 = *(const float4*)g, v1 = *(const float4*)(g + 4);
        st16(As + row * 76 + kc,
             make_uint4(pk2ru(v0.x, v0.y), pk2ru(v0.z, v0.w),
                        pk2ru(v1.x, v1.y), pk2ru(v1.z, v1.w)));
      }
#pragma unroll
      for (int i = 0; i < 2; i++) {          // B: 64 rows x 8 chunks(8)
        int c = t + i * 256;
        int row = c >> 3, kc = (c & 7) << 3;
        const float* g = W + (bnn + row) * ND + k0 + kc;
        float4 v0 = *(const float4*)g, v1 = *(const float4*)(g + 4);
        st16(Bs + row * 76 + kc,
             make_uint4(pk2ru(v0.x, v0.y), pk2ru(v0.z, v0.w),
                        pk2ru(v1.x, v1.y), pk2ru(v1.z, v1.w)));
      }
      __syncthreads();
#pragma unroll
      for (int ks = 0; ks < 4; ks++) {
        bf16x8 A = ld8(af + ks * 16);
        acc0 = __builtin_amdgcn_mfma_f32_32x32x16_bf16(A, ld8(bf0 + ks * 16), acc0, 0, 0, 0);
        acc1 = __builtin_amdgcn_mfma_f32_32x32x16_bf16(A, ld8(bf1 + ks * 16), acc1, 0, 0, 0);
      }
    }
    __syncthreads();                         // reuse As as epilogue Tile
    if (z < 2) {
      unsigned short* Tile = As;             // [128 rows][64 cols] stride 68
      unsigned short* Y = (z == 0) ? Qp : Kp;
      const float sc = (z == 0) ? SCALE2 : 1.0f;
      const unsigned int padw = (z == 0) ? 0xC200u : 0x3F80u;  // -32.0 : 1.0
#pragma unroll
      for (int r2 = 0; r2 < 16; r2++) {
        int lr = m0 + (r2 & 3) + 8 * (r2 >> 2) + 4 * hi;
        Tile[lr * 68 + l31] = f2bru(acc0[r2] * sc);
        Tile[lr * 68 + 32 + l31] = f2bru(acc1[r2] * sc);
      }
      __syncthreads();
#pragma unroll
      for (int i = 0; i < 4; i++) {          // 128 rows x 8 chunks
        int c = t + i * 256;
        int row = c >> 3, ch = c & 7;
        int j = bnn + ch * 8;
        int h = j / 40, dh = j - h * 40;
        uint4 v = ld16u(Tile + row * 68 + ch * 8);
        st16(Y + h * HS48 + (bm + row) * 48 + dh, v);
        if (dh == 0)
          st16(Y + h * HS48 + (bm + row) * 48 + 40, make_uint4(padw, 0u, 0u, 0u));
      }
    } else {
      unsigned short* Tile = As;             // transposed [64 j][128 s] str 132
#pragma unroll
      for (int r2 = 0; r2 < 16; r2++) {
        int lr = m0 + (r2 & 3) + 8 * (r2 >> 2) + 4 * hi;
        Tile[l31 * 132 + lr] = f2bru(acc0[r2]);
        Tile[(32 + l31) * 132 + lr] = f2bru(acc1[r2]);
      }
      __syncthreads();
#pragma unroll
      for (int i = 0; i < 4; i++) {          // 64 j-rows x 16 s-chunks
        int c = t + i * 256;
        int row = c >> 4, ch = c & 15;
        int j = bnn + row;
        int h = j / 40, dd = j - h * 40;
        uint4 v = ld16u(Tile + row * 132 + ch * 8);
        st16(Vt + h * VTH + dd * NS + bm + ch * 8, v);
      }
    }
  }
  gridbar(bar + 0, 1024);

  // ================= Phase B: MFMA flash attention =================
  {
    const int h = b & 7, ks = (b >> 3) & 3, qt = b >> 5;   // qt 0..31
    unsigned short* Ks = (unsigned short*)smem;            // [m-row][48], str 68
    unsigned short* Vs = (unsigned short*)(smem + 8704);   // [dh][64], str 68
    for (int i = t; i < 272; i += 256)
      ((unsigned int*)(Vs + 40 * 68))[i] = (i < 34) ? 0x3F803F80u : 0u;

    const int kbase = ks * 1024;
    const int qbase = qt * 128 + w * 32;
    const unsigned short* qp = Qp + h * HS48 + (qbase + l31) * 48 + hi * 8;
    bf16x8 qf0 = *(const bf16x8*)qp;
    bf16x8 qf1 = *(const bf16x8*)(qp + 16);
    bf16x8 qf2 = *(const bf16x8*)(qp + 32);  // includes {-32,0..} pad

    f32x16 oa0 = {0,0,0,0,0,0,0,0,0,0,0,0,0,0,0,0};
    f32x16 oa1 = {0,0,0,0,0,0,0,0,0,0,0,0,0,0,0,0};

    const int kr0 = t / 6, kc0 = t - kr0 * 6;
    const int kr1 = (t + 256) / 6, kc1 = (t + 256) - kr1 * 6;
    const unsigned short* gK0 = Kp + h * HS48 + (kbase + kr0) * 48 + kc0 * 8;
    const unsigned short* gK1 = Kp + h * HS48 + (kbase + kr1) * 48 + kc1 * 8;
    unsigned short* lK0 = Ks + ((kr0 & 32) | sig32v(kr0 & 31)) * 68 + kc0 * 8;
    unsigned short* lK1 = Ks + ((kr1 & 32) | sig32v(kr1 & 31)) * 68 + kc1 * 8;
    const int vr0 = t >> 3, vc = t & 7, vr1 = 32 + vr0;
    const unsigned short* gV0 = Vt + h * VTH + vr0 * NS + kbase + vc * 8;
    const unsigned short* gV1 = Vt + h * VTH + vr1 * NS + kbase + vc * 8;
    unsigned short* lV0 = Vs + vr0 * 68 + vc * 8;
    unsigned short* lV1 = Vs + vr1 * 68 + vc * 8;

    const unsigned short* kf0 = Ks + l31 * 68 + hi * 8;
    const unsigned short* kf1 = Ks + (32 + l31) * 68 + hi * 8;
    const unsigned short* vf0 = Vs + l31 * 68 + hi * 8;
    const unsigned short* vf1 = Vs + (32 + (l31 & 15)) * 68 + hi * 8;

    uint4 ka = *(const uint4*)gK0;
    uint4 kb2, vb2;
    uint4 va = *(const uint4*)gV0;
    if (t < 128) kb2 = *(const uint4*)gK1;
    if (t < 64)  vb2 = *(const uint4*)gV1;

    for (int it = 0; it < 16; ++it) {
      __syncthreads();
      st16(lK0, ka);
      if (t < 128) st16(lK1, kb2);
      st16(lV0, va);
      if (t < 64) st16(lV1, vb2);
      __syncthreads();
      // prefetch next tile (last-iter overrun lands in adjacent ws buffers)
      gK0 += 64 * 48; gK1 += 64 * 48; gV0 += 64; gV1 += 64;
      ka = *(const uint4*)gK0;
      va = *(const uint4*)gV0;
      if (t < 128) kb2 = *(const uint4*)gK1;
      if (t < 64)  vb2 = *(const uint4*)gV1;

      {  // m-tile 0: phys keys 0..31 (sigma rows)
        f32x16 s0 = {0,0,0,0,0,0,0,0,0,0,0,0,0,0,0,0};
        s0 = __builtin_amdgcn_mfma_f32_32x32x16_bf16(ld8(kf0), qf0, s0, 0, 0, 0);
        s0 = __builtin_amdgcn_mfma_f32_32x32x16_bf16(ld8(kf0 + 16), qf1, s0, 0, 0, 0);
        s0 = __builtin_amdgcn_mfma_f32_32x32x16_bf16(ld8(kf0 + 32), qf2, s0, 0, 0, 0);
        unsigned int pw[8];
#pragma unroll
        for (int i = 0; i < 8; i++)
          pw[i] = pk2t(fexp2(s0[2 * i]), fexp2(s0[2 * i + 1]));
        bf16x8 pf0 = __builtin_bit_cast(bf16x8, make_uint4(pw[0], pw[1], pw[2], pw[3]));
        bf16x8 pf1 = __builtin_bit_cast(bf16x8, make_uint4(pw[4], pw[5], pw[6], pw[7]));
        oa0 = __builtin_amdgcn_mfma_f32_32x32x16_bf16(pf0, ld8(vf0), oa0, 0, 0, 0);
        oa1 = __builtin_amdgcn_mfma_f32_32x32x16_bf16(pf0, ld8(vf1), oa1, 0, 0, 0);
        oa0 = __builtin_amdgcn_mfma_f32_32x32x16_bf16(pf1, ld8(vf0 + 16), oa0, 0, 0, 0);
        oa1 = __builtin_amdgcn_mfma_f32_32x32x16_bf16(pf1, ld8(vf1 + 16), oa1, 0, 0, 0);
      }
      {  // m-tile 1: phys keys 32..63
        f32x16 s1 = {0,0,0,0,0,0,0,0,0,0,0,0,0,0,0,0};
        s1 = __builtin_amdgcn_mfma_f32_32x32x16_bf16(ld8(kf1), qf0, s1, 0, 0, 0);
        s1 = __builtin_amdgcn_mfma_f32_32x32x16_bf16(ld8(kf1 + 16), qf1, s1, 0, 0, 0);
        s1 = __builtin_amdgcn_mfma_f32_32x32x16_bf16(ld8(kf1 + 32), qf2, s1, 0, 0, 0);
        unsigned int pw[8];
#pragma unroll
        for (int i = 0; i < 8; i++)
          pw[i] = pk2t(fexp2(s1[2 * i]), fexp2(s1[2 * i + 1]));
        bf16x8 pf2 = __builtin_bit_cast(bf16x8, make_uint4(pw[0], pw[1], pw[2], pw[3]));
        bf16x8 pf3 = __builtin_bit_cast(bf16x8, make_uint4(pw[4], pw[5], pw[6], pw[7]));
        oa0 = __builtin_amdgcn_mfma_f32_32x32x16_bf16(pf2, ld8(vf0 + 32), oa0, 0, 0, 0);
        oa1 = __builtin_amdgcn_mfma_f32_32x32x16_bf16(pf2, ld8(vf1 + 32), oa1, 0, 0, 0);
        oa0 = __builtin_amdgcn_mfma_f32_32x32x16_bf16(pf3, ld8(vf0 + 48), oa0, 0, 0, 0);
        oa1 = __builtin_amdgcn_mfma_f32_32x32x16_bf16(pf3, ld8(vf1 + 48), oa1, 0, 0, 0);
      }
    }

    unsigned short* opb = Op + ks * XN + h * 163840;
    float* lpb = Lp + ks * 32768 + h * NS;
#pragma unroll
    for (int r2 = 0; r2 < 16; r2++) {
      int qr = qbase + (r2 & 3) + 8 * (r2 >> 2) + 4 * hi;
      opb[qr * 40 + l31] = f2bru(oa0[r2]);
      if (l31 < 8) opb[qr * 40 + 32 + l31] = f2bru(oa1[r2]);
      if (l31 == 8) lpb[qr] = oa1[r2];   // l = Sum(p) via ones-row at dh=40
    }
  }
  gridbar(bar + 1, 1024);

  // ================= Phase C: combine 4 partials -> Xo =================
  for (int i = b * 256 + t; i < 655360; i += 262144) {
    int e = i * 2;                          // over [h][s][40] pairs
    int h2 = e / 163840;
    int r2 = e - h2 * 163840;
    int s2 = r2 / 40;
    int dh2 = r2 - s2 * 40;
    float a0 = 0.f, a1 = 0.f, ls = 0.f;
#pragma unroll
    for (int k = 0; k < 4; k++) {
      unsigned int uo = *(const unsigned int*)(Op + k * XN + e);
      a0 += __builtin_bit_cast(float, uo << 16);
      a1 += __builtin_bit_cast(float, uo & 0xFFFF0000u);
      ls += Lp[k * 32768 + h2 * NS + s2];
    }
    float inv = 1.0f / ls;
    *(unsigned int*)(Xo + s2 * ND + h2 * 40 + dh2) = pk2ru(a0 * inv, a1 * inv);
  }
  gridbar(bar + 2, 1024);

  // ================= Phase D: out projection (320 units) =================
  if (((b * 5) & 15) < 5) {
    const int u = (b * 5) >> 4;              // 0..319 bijective over actives
    const int bm = (u / 5) * 64, bn = (u % 5) * 64;
    unsigned short* As = (unsigned short*)smem;            // 64*36
    unsigned short* Bs = (unsigned short*)(smem + 4608);
    const int m0 = (w & 1) * 32, n0 = (w >> 1) * 32;
    f32x16 acc = {0,0,0,0,0,0,0,0,0,0,0,0,0,0,0,0};
    const int ar = t >> 2, ac = t & 3;
    const unsigned short* gA = Xo + (bm + ar) * ND + ac * 8;
    const float* gB = Wo + (bn + ar) * ND + ac * 8;
    unsigned short* lA = As + ar * 36 + ac * 8;
    unsigned short* lB = Bs + ar * 36 + ac * 8;
    const unsigned short* af = As + (m0 + l31) * 36 + hi * 8;
    const unsigned short* bf = Bs + (n0 + l31) * 36 + hi * 8;
    uint4 a = *(const uint4*)gA;
    float4 b0 = *(const float4*)gB, b1 = *(const float4*)(gB + 4);
    for (int k0 = 0; k0 < ND; k0 += 32) {
      __syncthreads();
      st16(lA, a);
      st16(lB, make_uint4(pk2ru(b0.x, b0.y), pk2ru(b0.z, b0.w),
                          pk2ru(b1.x, b1.y), pk2ru(b1.z, b1.w)));
      __syncthreads();
      if (k0 + 32 < ND) {
        gA += 32; gB += 32;
        a = *(const uint4*)gA;
        b0 = *(const float4*)gB; b1 = *(const float4*)(gB + 4);
      }
      bf16x8 A0 = ld8(af), A1 = ld8(af + 16);
      bf16x8 B0 = ld8(bf), B1 = ld8(bf + 16);
      acc = __builtin_amdgcn_mfma_f32_32x32x16_bf16(A0, B0, acc, 0, 0, 0);
      acc = __builtin_amdgcn_mfma_f32_32x32x16_bf16(A1, B1, acc, 0, 0, 0);
    }
    const int j = bn + n0 + l31;
    const float bj = bo[j];
#pragma unroll
    for (int r2 = 0; r2 < 16; r2++) {
      int row = bm + m0 + (r2 & 3) + 8 * (r2 >> 2) + 4 * hi;
      out[row * ND + j] = acc[r2] + bj;
    }
  }
}

extern "C" void kernel_launch(void* const* d_in, const int* in_sizes, int n_in,
                              void* d_out, int out_size, void* d_ws, size_t ws_size,
                              hipStream_t stream) {
  (void)in_sizes; (void)n_in; (void)out_size; (void)ws_size;
  const float* x  = (const float*)d_in[0];
  const float* Wq = (const float*)d_in[1];
  const float* Wk = (const float*)d_in[2];
  const float* Wv = (const float*)d_in[3];
  const float* Wo = (const float*)d_in[4];
  const float* bo = (const float*)d_in[5];
  float* out = (float*)d_out;

  unsigned short* Qp = (unsigned short*)d_ws;   // 8*HS48
  unsigned short* Kp = Qp + 8 * HS48;           // 8*HS48
  unsigned short* Vt = Kp + 8 * HS48;           // 8*VTH
  unsigned short* Op = Vt + 8 * VTH;            // 4*XN bf16 partials
  unsigned short* Xo = Op + 4 * XN;             // XN
  float* Lp = (float*)(Xo + XN);                // 4*32768 fp32
  unsigned int* bar = (unsigned int*)(Lp + 4 * 32768);  // 16 counters
  // ws use ~22.6 MB

  hipMemsetAsync(bar, 0, 64, stream);           // zero barrier counters
  mega_kernel<<<dim3(1024), dim3(256), 0, stream>>>(
      x, Wq, Wk, Wv, Wo, bo, out, Qp, Kp, Vt, Op, Xo, Lp, bar);
}

// Round 11
// 434.254 us; speedup vs baseline: 1.4723x; 1.4723x over previous
//
#include <hip/hip_runtime.h>
#include <math.h>

// B=1, S=4096, H=8, DH=40, D=320, fp32 in/out.  THREE kernels:
// proj_qkv: 128x64-tile MFMA GEMM (BK=64) -> Qp/Kp [h][s][48] (Q pre-scaled;
//           pad carries -32 offset), Vt [h][40][4096].   [R9, validated]
// attn:     MFMA flash (R9 core): ks=8 split, sigma-permuted K so QK C/D regs
//           ARE PV A-frags, p = raw v_exp_f32, l via ones-row, PLUS fused
//           combine: last-arriving ks-block per (h,qt) (atomic ticket)
//           sums the 8 partials and writes normalized Xo. No spin/wait.
// proj_out: 128x64-tile MFMA GEMM + bias -> out fp32.    [R9, validated]

#define NS 4096
#define ND 320
#define SCALE2 0.2281101152f      // log2(e)/sqrt(40)
#define HS48 196608               // 4096*48 per head
#define VTH 163840                // 40*4096 per head
#define XN 1310720

typedef __attribute__((ext_vector_type(8))) short bf16x8;
typedef __attribute__((ext_vector_type(16))) float f32x16;

static __device__ __forceinline__ unsigned short f2bru(float f) {
  return (unsigned short)((__builtin_bit_cast(unsigned int, f) + 0x8000u) >> 16);
}
static __device__ __forceinline__ unsigned int pk2ru(float a, float b) {
  unsigned int ua = __builtin_bit_cast(unsigned int, a) + 0x8000u;
  unsigned int ub = __builtin_bit_cast(unsigned int, b) + 0x8000u;
  return __builtin_amdgcn_perm(ub, ua, 0x07060302u);
}
static __device__ __forceinline__ unsigned int pk2t(float a, float b) {
  return __builtin_amdgcn_perm(__builtin_bit_cast(unsigned int, b),
                               __builtin_bit_cast(unsigned int, a), 0x07060302u);
}
static __device__ __forceinline__ float fexp2(float x) {
  return __builtin_amdgcn_exp2f(x);
}
static __device__ __forceinline__ bf16x8 ld8(const unsigned short* p) {
  union { uint2 u[2]; bf16x8 v; } c;
  c.u[0] = *(const uint2*)p;
  c.u[1] = *(const uint2*)(p + 4);
  return c.v;
}
static __device__ __forceinline__ uint4 ld16u(const unsigned short* p) {
  uint2 a = *(const uint2*)p, b = *(const uint2*)(p + 4);
  return make_uint4(a.x, a.y, b.x, b.y);
}
static __device__ __forceinline__ void st16(unsigned short* p, uint4 v) {
  *(uint2*)p = make_uint2(v.x, v.y);
  *(uint2*)(p + 4) = make_uint2(v.z, v.w);
}
// sigma: phys key (0..31) -> MFMA m-row so QK C/D regs land in PV A order
static __device__ __forceinline__ int sig32v(int q) {
  int s = q >> 4, h2 = (q >> 3) & 1, j = q & 7;
  return (s << 4) | ((j >> 2) << 3) | (h2 << 2) | (j & 3);
}

// ---------------------------------------------------------------------------
// Kernel 1: q/k/v = x @ W^T. 128x64 tile, BK=64, 5 K-iters. grid (32, 15).
// ---------------------------------------------------------------------------
__global__ __launch_bounds__(256) void proj_qkv_kernel(
    const float* __restrict__ x, const float* __restrict__ Wq,
    const float* __restrict__ Wk, const float* __restrict__ Wv,
    unsigned short* __restrict__ Qp, unsigned short* __restrict__ Kp,
    unsigned short* __restrict__ Vt) {
  const int zi = blockIdx.y;
  const int z = zi / 5;
  const int bnn = (zi - z * 5) * 64;
  const float* W = (z == 0) ? Wq : (z == 1) ? Wk : Wv;
  __shared__ __align__(16) unsigned short As[128 * 76];  // stride 38 dw: 2-way
  __shared__ __align__(16) unsigned short Bs[64 * 76];
  const int t = threadIdx.x;
  const int w = t >> 6, l = t & 63, l31 = l & 31, hi = l >> 5;
  const int bm = blockIdx.x * 128;
  const int m0 = w * 32;
  f32x16 acc0 = {0,0,0,0,0,0,0,0,0,0,0,0,0,0,0,0};
  f32x16 acc1 = {0,0,0,0,0,0,0,0,0,0,0,0,0,0,0,0};
  const unsigned short* af = As + (m0 + l31) * 76 + hi * 8;
  const unsigned short* bf0 = Bs + l31 * 76 + hi * 8;
  const unsigned short* bf1 = Bs + (32 + l31) * 76 + hi * 8;
  for (int k0 = 0; k0 < ND; k0 += 64) {
    __syncthreads();
#pragma unroll
    for (int i = 0; i < 4; i++) {            // A: 128 rows x 8 chunks(8)
      int c = t + i * 256;
      int row = c >> 3, kc = (c & 7) << 3;
      const float* g = x + (bm + row) * ND + k0 + kc;
      float4 v0 = *(const float4*)g, v1 = *(const float4*)(g + 4);
      st16(As + row * 76 + kc,
           make_uint4(pk2ru(v0.x, v0.y), pk2ru(v0.z, v0.w),
                      pk2ru(v1.x, v1.y), pk2ru(v1.z, v1.w)));
    }
#pragma unroll
    for (int i = 0; i < 2; i++) {            // B: 64 rows x 8 chunks(8)
      int c = t + i * 256;
      int row = c >> 3, kc = (c & 7) << 3;
      const float* g = W + (bnn + row) * ND + k0 + kc;
      float4 v0 = *(const float4*)g, v1 = *(const float4*)(g + 4);
      st16(Bs + row * 76 + kc,
           make_uint4(pk2ru(v0.x, v0.y), pk2ru(v0.z, v0.w),
                      pk2ru(v1.x, v1.y), pk2ru(v1.z, v1.w)));
    }
    __syncthreads();
#pragma unroll
    for (int ks = 0; ks < 4; ks++) {
      bf16x8 A = ld8(af + ks * 16);
      acc0 = __builtin_amdgcn_mfma_f32_32x32x16_bf16(A, ld8(bf0 + ks * 16), acc0, 0, 0, 0);
      acc1 = __builtin_amdgcn_mfma_f32_32x32x16_bf16(A, ld8(bf1 + ks * 16), acc1, 0, 0, 0);
    }
  }
  __syncthreads();                           // reuse As as epilogue Tile
  if (z < 2) {
    unsigned short* Tile = As;               // [128 rows][64 cols] stride 68
    unsigned short* Y = (z == 0) ? Qp : Kp;
    const float sc = (z == 0) ? SCALE2 : 1.0f;
    const unsigned int padw = (z == 0) ? 0xC200u : 0x3F80u;  // -32.0 : 1.0
#pragma unroll
    for (int r2 = 0; r2 < 16; r2++) {
      int lr = m0 + (r2 & 3) + 8 * (r2 >> 2) + 4 * hi;
      Tile[lr * 68 + l31] = f2bru(acc0[r2] * sc);
      Tile[lr * 68 + 32 + l31] = f2bru(acc1[r2] * sc);
    }
    __syncthreads();
#pragma unroll
    for (int i = 0; i < 4; i++) {            // 128 rows x 8 chunks
      int c = t + i * 256;
      int row = c >> 3, ch = c & 7;
      int j = bnn + ch * 8;
      int h = j / 40, dh = j - h * 40;
      uint4 v = ld16u(Tile + row * 68 + ch * 8);
      st16(Y + h * HS48 + (bm + row) * 48 + dh, v);
      if (dh == 0)
        st16(Y + h * HS48 + (bm + row) * 48 + 40, make_uint4(padw, 0u, 0u, 0u));
    }
  } else {
    unsigned short* Tile = As;               // transposed [64 j][128 s] str 132
#pragma unroll
    for (int r2 = 0; r2 < 16; r2++) {
      int lr = m0 + (r2 & 3) + 8 * (r2 >> 2) + 4 * hi;
      Tile[l31 * 132 + lr] = f2bru(acc0[r2]);
      Tile[(32 + l31) * 132 + lr] = f2bru(acc1[r2]);
    }
    __syncthreads();
#pragma unroll
    for (int i = 0; i < 4; i++) {            // 64 j-rows x 16 s-chunks
      int c = t + i * 256;
      int row = c >> 4, ch = c & 15;
      int j = bnn + row;
      int h = j / 40, dd = j - h * 40;
      uint4 v = ld16u(Tile + row * 132 + ch * 8);
      st16(Vt + h * VTH + dd * NS + bm + ch * 8, v);
    }
  }
}

// ---------------------------------------------------------------------------
// Kernel 2: MFMA flash attention + fused combine. grid 2048 x 256.
// h=b&7 XCD swizzle, ks=8 splits, 8 iters of 64-key tiles. After storing
// partials, each block tickets (h,qt); the LAST arrival (no waiting) sums
// the 8 partials for its 128 queries and writes normalized Xo.
// ---------------------------------------------------------------------------
__global__ __launch_bounds__(256) void attn_kernel(
    const unsigned short* __restrict__ Qp, const unsigned short* __restrict__ Kp,
    const unsigned short* __restrict__ Vt, unsigned short* __restrict__ Op,
    float* __restrict__ Lp, unsigned short* __restrict__ Xo,
    unsigned int* __restrict__ tickets) {
  const int b = blockIdx.x;
  const int h = b & 7, ks = (b >> 3) & 7, qt = b >> 6;
  const int t = threadIdx.x;
  const int w = t >> 6, l = t & 63, l31 = l & 31, hi = l >> 5;
  __shared__ __align__(16) unsigned short Ks[64 * 68];   // [m-row][48 used]
  __shared__ __align__(16) unsigned short Vs[48 * 68];   // [dh][64 keys]
  __shared__ int sLast;
  for (int i = t; i < 272; i += 256)
    ((unsigned int*)(Vs + 40 * 68))[i] = (i < 34) ? 0x3F803F80u : 0u;

  const int kbase = ks * 512;
  const int qbase = qt * 128 + w * 32;
  const unsigned short* qp = Qp + h * HS48 + (qbase + l31) * 48 + hi * 8;
  bf16x8 qf0 = *(const bf16x8*)qp;
  bf16x8 qf1 = *(const bf16x8*)(qp + 16);
  bf16x8 qf2 = *(const bf16x8*)(qp + 32);   // includes {-32,0..} pad

  f32x16 oa0 = {0,0,0,0,0,0,0,0,0,0,0,0,0,0,0,0};
  f32x16 oa1 = {0,0,0,0,0,0,0,0,0,0,0,0,0,0,0,0};

  const int kr0 = t / 6, kc0 = t - kr0 * 6;
  const int kr1 = (t + 256) / 6, kc1 = (t + 256) - kr1 * 6;
  const unsigned short* gK0 = Kp + h * HS48 + (kbase + kr0) * 48 + kc0 * 8;
  const unsigned short* gK1 = Kp + h * HS48 + (kbase + kr1) * 48 + kc1 * 8;
  unsigned short* lK0 = Ks + ((kr0 & 32) | sig32v(kr0 & 31)) * 68 + kc0 * 8;
  unsigned short* lK1 = Ks + ((kr1 & 32) | sig32v(kr1 & 31)) * 68 + kc1 * 8;
  const int vr0 = t >> 3, vc = t & 7, vr1 = 32 + vr0;
  const unsigned short* gV0 = Vt + h * VTH + vr0 * NS + kbase + vc * 8;
  const unsigned short* gV1 = Vt + h * VTH + vr1 * NS + kbase + vc * 8;
  unsigned short* lV0 = Vs + vr0 * 68 + vc * 8;
  unsigned short* lV1 = Vs + vr1 * 68 + vc * 8;

  const unsigned short* kf0 = Ks + l31 * 68 + hi * 8;
  const unsigned short* kf1 = Ks + (32 + l31) * 68 + hi * 8;
  const unsigned short* vf0 = Vs + l31 * 68 + hi * 8;
  const unsigned short* vf1 = Vs + (32 + (l31 & 15)) * 68 + hi * 8;

  uint4 ka = *(const uint4*)gK0;
  uint4 kb2, vb2;
  uint4 va = *(const uint4*)gV0;
  if (t < 128) kb2 = *(const uint4*)gK1;
  if (t < 64)  vb2 = *(const uint4*)gV1;

  for (int it = 0; it < 8; ++it) {
    __syncthreads();
    st16(lK0, ka);
    if (t < 128) st16(lK1, kb2);
    st16(lV0, va);
    if (t < 64) st16(lV1, vb2);
    __syncthreads();
    // prefetch next tile (last-iter overrun lands in adjacent ws buffers)
    gK0 += 64 * 48; gK1 += 64 * 48; gV0 += 64; gV1 += 64;
    ka = *(const uint4*)gK0;
    va = *(const uint4*)gV0;
    if (t < 128) kb2 = *(const uint4*)gK1;
    if (t < 64)  vb2 = *(const uint4*)gV1;

    {  // m-tile 0: phys keys 0..31 (sigma rows)
      f32x16 s0 = {0,0,0,0,0,0,0,0,0,0,0,0,0,0,0,0};
      s0 = __builtin_amdgcn_mfma_f32_32x32x16_bf16(ld8(kf0), qf0, s0, 0, 0, 0);
      s0 = __builtin_amdgcn_mfma_f32_32x32x16_bf16(ld8(kf0 + 16), qf1, s0, 0, 0, 0);
      s0 = __builtin_amdgcn_mfma_f32_32x32x16_bf16(ld8(kf0 + 32), qf2, s0, 0, 0, 0);
      unsigned int pw[8];
#pragma unroll
      for (int i = 0; i < 8; i++)
        pw[i] = pk2t(fexp2(s0[2 * i]), fexp2(s0[2 * i + 1]));
      bf16x8 pf0 = __builtin_bit_cast(bf16x8, make_uint4(pw[0], pw[1], pw[2], pw[3]));
      bf16x8 pf1 = __builtin_bit_cast(bf16x8, make_uint4(pw[4], pw[5], pw[6], pw[7]));
      oa0 = __builtin_amdgcn_mfma_f32_32x32x16_bf16(pf0, ld8(vf0), oa0, 0, 0, 0);
      oa1 = __builtin_amdgcn_mfma_f32_32x32x16_bf16(pf0, ld8(vf1), oa1, 0, 0, 0);
      oa0 = __builtin_amdgcn_mfma_f32_32x32x16_bf16(pf1, ld8(vf0 + 16), oa0, 0, 0, 0);
      oa1 = __builtin_amdgcn_mfma_f32_32x32x16_bf16(pf1, ld8(vf1 + 16), oa1, 0, 0, 0);
    }
    {  // m-tile 1: phys keys 32..63
      f32x16 s1 = {0,0,0,0,0,0,0,0,0,0,0,0,0,0,0,0};
      s1 = __builtin_amdgcn_mfma_f32_32x32x16_bf16(ld8(kf1), qf0, s1, 0, 0, 0);
      s1 = __builtin_amdgcn_mfma_f32_32x32x16_bf16(ld8(kf1 + 16), qf1, s1, 0, 0, 0);
      s1 = __builtin_amdgcn_mfma_f32_32x32x16_bf16(ld8(kf1 + 32), qf2, s1, 0, 0, 0);
      unsigned int pw[8];
#pragma unroll
      for (int i = 0; i < 8; i++)
        pw[i] = pk2t(fexp2(s1[2 * i]), fexp2(s1[2 * i + 1]));
      bf16x8 pf2 = __builtin_bit_cast(bf16x8, make_uint4(pw[0], pw[1], pw[2], pw[3]));
      bf16x8 pf3 = __builtin_bit_cast(bf16x8, make_uint4(pw[4], pw[5], pw[6], pw[7]));
      oa0 = __builtin_amdgcn_mfma_f32_32x32x16_bf16(pf2, ld8(vf0 + 32), oa0, 0, 0, 0);
      oa1 = __builtin_amdgcn_mfma_f32_32x32x16_bf16(pf2, ld8(vf1 + 32), oa1, 0, 0, 0);
      oa0 = __builtin_amdgcn_mfma_f32_32x32x16_bf16(pf3, ld8(vf0 + 48), oa0, 0, 0, 0);
      oa1 = __builtin_amdgcn_mfma_f32_32x32x16_bf16(pf3, ld8(vf1 + 48), oa1, 0, 0, 0);
    }
  }

  unsigned short* opb = Op + ks * XN + h * 163840;
  float* lpb = Lp + ks * 32768 + h * NS;
#pragma unroll
  for (int r2 = 0; r2 < 16; r2++) {
    int qr = qbase + (r2 & 3) + 8 * (r2 >> 2) + 4 * hi;
    opb[qr * 40 + l31] = f2bru(oa0[r2]);
    if (l31 < 8) opb[qr * 40 + 32 + l31] = f2bru(oa1[r2]);
    if (l31 == 8) lpb[qr] = oa1[r2];   // l = Sum(p) via ones-row at dh=40
  }

  // ---- fused combine: last-arriving ks-block per (h,qt) does it ----
  __threadfence();                     // release partials
  if (t == 0) {
    unsigned int old = __hip_atomic_fetch_add(&tickets[(qt << 3) | h], 1u,
                                              __ATOMIC_ACQ_REL,
                                              __HIP_MEMORY_SCOPE_AGENT);
    sLast = (old == 7);
  }
  __syncthreads();
  if (sLast) {
    const int qb0 = qt * 128;
    for (int i = t; i < 2560; i += 256) {      // 128 q x 20 uint-pairs
      int qi = i / 20, du = i - qi * 20;
      int q = qb0 + qi;
      float a0 = 0.f, a1 = 0.f, ls = 0.f;
#pragma unroll
      for (int k = 0; k < 8; k++) {
        unsigned int uo =
            *(const unsigned int*)(Op + k * XN + h * 163840 + q * 40 + du * 2);
        a0 += __builtin_bit_cast(float, uo << 16);
        a1 += __builtin_bit_cast(float, uo & 0xFFFF0000u);
        ls += Lp[k * 32768 + h * NS + q];
      }
      float inv = 1.0f / ls;
      *(unsigned int*)(Xo + q * ND + h * 40 + du * 2) = pk2ru(a0 * inv, a1 * inv);
    }
  }
}

// ---------------------------------------------------------------------------
// Kernel 3: out = Xo @ Wo^T + bo. 128x64 tile, BK=64, 5 iters. grid (32, 5).
// ---------------------------------------------------------------------------
__global__ __launch_bounds__(256) void proj_out_kernel(
    const unsigned short* __restrict__ Xo, const float* __restrict__ Wo,
    const float* __restrict__ bo, float* __restrict__ out) {
  __shared__ __align__(16) unsigned short As[128 * 76];
  __shared__ __align__(16) unsigned short Bs[64 * 76];
  const int t = threadIdx.x;
  const int w = t >> 6, l = t & 63, l31 = l & 31, hi = l >> 5;
  const int bm = blockIdx.x * 128;
  const int bnn = blockIdx.y * 64;
  const int m0 = w * 32;
  f32x16 acc0 = {0,0,0,0,0,0,0,0,0,0,0,0,0,0,0,0};
  f32x16 acc1 = {0,0,0,0,0,0,0,0,0,0,0,0,0,0,0,0};
  const unsigned short* af = As + (m0 + l31) * 76 + hi * 8;
  const unsigned short* bf0 = Bs + l31 * 76 + hi * 8;
  const unsigned short* bf1 = Bs + (32 + l31) * 76 + hi * 8;
  for (int k0 = 0; k0 < ND; k0 += 64) {
    __syncthreads();
#pragma unroll
    for (int i = 0; i < 4; i++) {            // A: 128 rows x 8 chunks, bf16 src
      int c = t + i * 256;
      int row = c >> 3, kc = (c & 7) << 3;
      uint4 v = *(const uint4*)(Xo + (bm + row) * ND + k0 + kc);
      st16(As + row * 76 + kc, v);
    }
#pragma unroll
    for (int i = 0; i < 2; i++) {            // B: 64 rows x 8 chunks, fp32 src
      int c = t + i * 256;
      int row = c >> 3, kc = (c & 7) << 3;
      const float* g = Wo + (bnn + row) * ND + k0 + kc;
      float4 v0 = *(const float4*)g, v1 = *(const float4*)(g + 4);
      st16(Bs + row * 76 + kc,
           make_uint4(pk2ru(v0.x, v0.y), pk2ru(v0.z, v0.w),
                      pk2ru(v1.x, v1.y), pk2ru(v1.z, v1.w)));
    }
    __syncthreads();
#pragma unroll
    for (int ks = 0; ks < 4; ks++) {
      bf16x8 A = ld8(af + ks * 16);
      acc0 = __builtin_amdgcn_mfma_f32_32x32x16_bf16(A, ld8(bf0 + ks * 16), acc0, 0, 0, 0);
      acc1 = __builtin_amdgcn_mfma_f32_32x32x16_bf16(A, ld8(bf1 + ks * 16), acc1, 0, 0, 0);
    }
  }
  const int j0 = bnn + l31, j1 = bnn + 32 + l31;
  const float bj0 = bo[j0], bj1 = bo[j1];
#pragma unroll
  for (int r2 = 0; r2 < 16; r2++) {
    int row = bm + m0 + (r2 & 3) + 8 * (r2 >> 2) + 4 * hi;
    out[row * ND + j0] = acc0[r2] + bj0;
    out[row * ND + j1] = acc1[r2] + bj1;
  }
}

extern "C" void kernel_launch(void* const* d_in, const int* in_sizes, int n_in,
                              void* d_out, int out_size, void* d_ws, size_t ws_size,
                              hipStream_t stream) {
  (void)in_sizes; (void)n_in; (void)out_size; (void)ws_size;
  const float* x  = (const float*)d_in[0];
  const float* Wq = (const float*)d_in[1];
  const float* Wk = (const float*)d_in[2];
  const float* Wv = (const float*)d_in[3];
  const float* Wo = (const float*)d_in[4];
  const float* bo = (const float*)d_in[5];
  float* out = (float*)d_out;

  unsigned short* Qp = (unsigned short*)d_ws;   // 8*HS48
  unsigned short* Kp = Qp + 8 * HS48;           // 8*HS48
  unsigned short* Vt = Kp + 8 * HS48;           // 8*VTH
  unsigned short* Xo = Vt + 8 * VTH;            // XN
  unsigned short* Op = Xo + XN;                 // 8*XN bf16 partials
  float* Lp = (float*)(Op + 8 * XN);            // 8*32768 fp32
  unsigned int* tickets = (unsigned int*)(Lp + 8 * 32768);  // 256 counters
  // ws use ~34 MB

  hipMemsetAsync(tickets, 0, 1024, stream);
  proj_qkv_kernel<<<dim3(32, 15), 256, 0, stream>>>(x, Wq, Wk, Wv, Qp, Kp, Vt);
  attn_kernel<<<dim3(2048), 256, 0, stream>>>(Qp, Kp, Vt, Op, Lp, Xo, tickets);
  proj_out_kernel<<<dim3(32, 5), 256, 0, stream>>>(Xo, Wo, bo, out);
}